// Round 11
// baseline (620.926 us; speedup 1.0000x reference)
//
#include <hip/hip_runtime.h>
#include <stdint.h>

// AttentionBlock: GroupNorm(32) -> 1x1 QKV -> 8-head legacy attention -> 1x1 proj -> residual
// B=2, C=512, H=W=64 (L=4096), heads=8, ch=64.
// attn v5: swapped 32x32x16 MFMA flash attention, fragment-order Q/K/V (coalesced dwordx4
// loads, no LDS in main loop), SPLIT-S across wave pairs (2x occupancy) with an
// online-softmax merge via LDS at the end. P-assembly uses HW-verified shfl_xor forms.

#define LTOK 4096
#define CDIM 512
#define NHEADS 8
#define EPS_GN 1e-6f
#define QKSCALE 0.3535533905932738f            // 1/sqrt(sqrt(64))
#define QSCL (0.3535533905932738f * 1.44269504088896f)  // LOG2E folded into q
#define FRAG_BH 262144                          // elems per bh in qF/kF/vF (=4096*64)

typedef float  f4   __attribute__((ext_vector_type(4)));
typedef float  f16v __attribute__((ext_vector_type(16)));
typedef short  bf8  __attribute__((ext_vector_type(8)));   // 8 bf16 as shorts
typedef unsigned short u16;
typedef unsigned short u16x8 __attribute__((ext_vector_type(8)));
typedef unsigned short u16x4 __attribute__((ext_vector_type(4)));
typedef uint32_t u32;
typedef uint32_t u32x2 __attribute__((ext_vector_type(2)));
typedef uint32_t u32x4 __attribute__((ext_vector_type(4)));

// T2 XOR swizzle for 128B-row LDS tiles (GEMM kernels): involution on 16B chunks.
#define SWZ(row, inrow) ((inrow) ^ (((row)&7)<<4))

__device__ __forceinline__ u16 f2bf(float f){
  uint32_t u = __builtin_bit_cast(uint32_t, f);
  u += 0x7FFFu + ((u>>16)&1u);           // RNE
  return (u16)(u>>16);
}
// width=16 global->LDS DMA (GEMM staging). LDS dest wave-uniform; global src per-lane.
__device__ __forceinline__ void gload16(const void* g, void* l){
  __builtin_amdgcn_global_load_lds(
      (const __attribute__((address_space(1))) uint32_t*)g,
      (__attribute__((address_space(3))) uint32_t*)l, 16, 0, 0);
}
__device__ __forceinline__ f4 mfma16(bf8 a, bf8 b, f4 c){
  return __builtin_amdgcn_mfma_f32_16x16x32_bf16(a, b, c, 0, 0, 0);
}
__device__ __forceinline__ f16v mfma32(bf8 a, bf8 b, f16v c){
  return __builtin_amdgcn_mfma_f32_32x32x16_bf16(a, b, c, 0, 0, 0);
}
__device__ __forceinline__ u32 cvtpk(float a, float b){
  u32 d;
  asm("v_cvt_pk_bf16_f32 %0, %1, %2" : "=v"(d) : "v"(a), "v"(b));
  return d;
}

// ---------------- GroupNorm ----------------
__global__ __launch_bounds__(256) void gn_stats(const float* __restrict__ x,
                                                float* __restrict__ stats){
  const int bg = blockIdx.x;                   // b*32+g
  const float* p = x + (size_t)bg * 16 * LTOK;
  float s1 = 0.f, s2 = 0.f;
  for (int i = threadIdx.x; i < 16*LTOK/4; i += 256){
    f4 v = ((const f4*)p)[i];
    s1 += v[0]+v[1]+v[2]+v[3];
    s2 += v[0]*v[0]+v[1]*v[1]+v[2]*v[2]+v[3]*v[3];
  }
  #pragma unroll
  for (int off=32; off; off>>=1){ s1 += __shfl_down(s1, off); s2 += __shfl_down(s2, off); }
  __shared__ float a1[4], a2[4];
  const int w = threadIdx.x>>6;
  if ((threadIdx.x&63)==0){ a1[w]=s1; a2[w]=s2; }
  __syncthreads();
  if (threadIdx.x==0){
    float t1 = a1[0]+a1[1]+a1[2]+a1[3];
    float t2 = a2[0]+a2[1]+a2[2]+a2[3];
    const float inv = 1.f/(16.f*LTOK);
    float mu  = t1*inv;
    float var = t2*inv - mu*mu;
    stats[bg*2]   = mu;
    stats[bg*2+1] = rsqrtf(var + EPS_GN);
  }
}

// normalize + transpose to xnT[b][l][c] bf16
__global__ __launch_bounds__(256) void gn_norm_t(
    const float* __restrict__ x, const float* __restrict__ gamma,
    const float* __restrict__ beta, const float* __restrict__ stats,
    u16* __restrict__ xnT){
  __shared__ float t[64][65];
  const int lb = blockIdx.x*64, cb = blockIdx.y*64, b = blockIdx.z;
  const int tid = threadIdx.x;
  {
    const int cl = tid>>4;         // 0..15
    const int ll = (tid&15)*4;     // 0..60
    #pragma unroll
    for (int rep=0; rep<4; rep++){
      const int cloc = rep*16 + cl;
      const int c = cb + cloc;
      const int grp = c>>4;
      const float mu = stats[(b*32+grp)*2];
      const float rs = stats[(b*32+grp)*2+1];
      const float ga = gamma[c], be = beta[c];
      f4 v = *(const f4*)(x + ((size_t)b*CDIM + c)*LTOK + lb + ll);
      t[cloc][ll+0] = (v[0]-mu)*rs*ga + be;
      t[cloc][ll+1] = (v[1]-mu)*rs*ga + be;
      t[cloc][ll+2] = (v[2]-mu)*rs*ga + be;
      t[cloc][ll+3] = (v[3]-mu)*rs*ga + be;
    }
  }
  __syncthreads();
  {
    const int l2 = tid>>2;            // 0..63
    const int c2 = (tid&3)*16;        // 0,16,32,48
    u16x8 o0, o1;
    #pragma unroll
    for (int j=0;j<8;j++){
      o0[j] = f2bf(t[c2+j][l2]);
      o1[j] = f2bf(t[c2+8+j][l2]);
    }
    u16* dst = xnT + ((size_t)b*LTOK + lb + l2)*CDIM + cb + c2;
    *(u16x8*)dst       = o0;
    *((u16x8*)dst + 1) = o1;
  }
}

// ---------------- f32 -> bf16 weight convert ----------------
__global__ __launch_bounds__(256) void cvt_bf16(const float* __restrict__ in,
                                                u16* __restrict__ out, int n4){
  int i = blockIdx.x*256 + threadIdx.x;
  if (i >= n4) return;
  f4 v = ((const f4*)in)[i];
  u16x4 o;
  o[0]=f2bf(v[0]); o[1]=f2bf(v[1]); o[2]=f2bf(v[2]); o[3]=f2bf(v[3]);
  ((u16x4*)out)[i] = o;
}

// ---------------- QKV GEMM ----------------
// D[l][o] = sum_c xnT[l][c] * W[o][c]
// epilogue writes FRAGMENT-ORDER q/k/v:
//   qF/kF[bh]: elem = ((tile32*4 + sl)*2 + h)*256 + row*8 + j   (t=tile32*32+row, c=16sl+8h+j)
//   vF[bh]:    elem = ((tile64*4 + ks)*2 + h)*512 + c*8 + j     (s=tile64*64+16ks+8h+j)
__global__ __launch_bounds__(256) void qkv_gemm(
    const u16* __restrict__ xnT, const u16* __restrict__ wqkv,
    const float* __restrict__ bqkv,
    u16* __restrict__ qF, u16* __restrict__ kF, u16* __restrict__ vF){
  __shared__ __align__(16) char lA[16384];   // [128 l][64 k] bf16, swizzled
  __shared__ __align__(16) char lB[16384];   // [128 o][64 k] bf16, swizzled
  const int l0 = blockIdx.x*128, o0 = blockIdx.y*128, b = blockIdx.z;
  const int tid = threadIdx.x, w = tid>>6, lane = tid&63;
  const int wm = w>>1, wn = w&1, fr = lane&15, g = lane>>4;
  f4 acc[4][4] = {};
  const char* Ab = (const char*)(xnT + ((size_t)b*LTOK + l0)*CDIM);
  const char* Bb = (const char*)(wqkv + (size_t)o0*CDIM);
  for (int kt=0; kt<8; kt++){
    #pragma unroll
    for (int j=0;j<4;j++){
      const int off = w*4096 + j*1024 + lane*16;
      const int row = off>>7, inrow = off&127;
      gload16(Ab + (size_t)row*1024 + kt*128 + SWZ(row,inrow), lA + w*4096 + j*1024);
      gload16(Bb + (size_t)row*1024 + kt*128 + SWZ(row,inrow), lB + w*4096 + j*1024);
    }
    __syncthreads();
    bf8 af[4][2], bfr[4][2];
    #pragma unroll
    for (int mt=0;mt<4;mt++){
      #pragma unroll
      for (int kk=0;kk<2;kk++){
        const int row = wm*64 + mt*16 + fr;
        af[mt][kk] = *(const bf8*)(lA + row*128 + SWZ(row, kk*64 + g*16));
      }
    }
    #pragma unroll
    for (int nt=0;nt<4;nt++){
      #pragma unroll
      for (int kk=0;kk<2;kk++){
        const int row = wn*64 + nt*16 + fr;
        bfr[nt][kk] = *(const bf8*)(lB + row*128 + SWZ(row, kk*64 + g*16));
      }
    }
    #pragma unroll
    for (int mt=0;mt<4;mt++){
      #pragma unroll
      for (int nt=0;nt<4;nt++){
        acc[mt][nt] = mfma16(af[mt][0], bfr[nt][0], acc[mt][nt]);
        acc[mt][nt] = mfma16(af[mt][1], bfr[nt][1], acc[mt][nt]);
      }
    }
    __syncthreads();
  }
  // lane holds D[l = l0+wm*64+mt*16+g*4+r_][o = o0+wn*64+nt*16+fr]
  #pragma unroll
  for (int nt=0;nt<4;nt++){
    const int o = o0 + wn*64 + nt*16 + fr;
    const float bias = bqkv[o];
    const int head = o / 192;
    int rr = o - head*192;                 // legacy interleave: [q|k|v] x 64 per head
    const int bh = b*NHEADS + head;
    if (rr < 128){
      u16* base; float sc;
      if (rr < 64){ base = qF; sc = QSCL; }
      else        { base = kF; sc = QKSCALE; rr -= 64; }
      const int sl = rr>>4, hq = (rr>>3)&1, j = rr&7;
      const int Tb = (l0 + wm*64)>>5;                  // tile32 base
      u16* p = base + (size_t)bh*FRAG_BH + (size_t)(sl*2 + hq)*256 + j;
      #pragma unroll
      for (int mt=0;mt<4;mt++){
        const size_t toff = (size_t)(Tb + (mt>>1))*2048 + (size_t)((mt&1)*16 + g*4)*8;
        #pragma unroll
        for (int r_=0;r_<4;r_++)
          p[toff + r_*8] = f2bf((acc[mt][nt][r_] + bias) * sc);
      }
    } else {
      rr -= 128;                                       // rr = c
      const int s64 = (l0>>6) + wm;
      u16* p = vF + (size_t)bh*FRAG_BH + (size_t)s64*4096 + (size_t)(g>>1)*512
                  + (size_t)rr*8 + (g&1)*4;
      #pragma unroll
      for (int mt=0;mt<4;mt++){                        // ks = mt
        u16x4 pk;
        #pragma unroll
        for (int r_=0;r_<4;r_++) pk[r_] = f2bf(acc[mt][nt][r_] + bias);
        *(u16x4*)(p + mt*1024) = pk;
      }
    }
  }
}

// ---------------- flash attention v5 (split-S wave pairs) ----------------
__device__ __forceinline__ void loadKF(const u16* kl, int t64, bf8 k0[4], bf8 k1[4]){
  const u16* p = kl + (size_t)t64*4096;
  #pragma unroll
  for (int sl=0; sl<4; sl++){
    k0[sl] = *(const bf8*)(p + sl*512);           // s rows t64*64 + r
    k1[sl] = *(const bf8*)(p + 2048 + sl*512);    // s rows +32
  }
}
__device__ __forceinline__ void loadVF(const u16* vl, int t64, bf8 v0[4], bf8 v1[4]){
  const u16* p = vl + (size_t)t64*4096;
  #pragma unroll
  for (int ks=0; ks<4; ks++){
    v0[ks] = *(const bf8*)(p + ks*1024);          // c rows 0..31
    v1[ks] = *(const bf8*)(p + ks*1024 + 256);    // c rows 32..63
  }
}
// Build one PV B-fragment (k-slice of 16 s) from 4 packed u32 (P pairs).
// HW-VERIFIED form (rounds 6/10 passed validation with this exact structure).
__device__ __forceinline__ bf8 pfrag(u32 a0, u32 a1, u32 a2, u32 a3, bool hb){
  u32 x0 = (u32)__shfl_xor((int)a2, 32);
  u32 x1 = (u32)__shfl_xor((int)a3, 32);
  u32 x2 = (u32)__shfl_xor((int)a0, 32);
  u32 x3 = (u32)__shfl_xor((int)a1, 32);
  u32x4 w;
  w[0] = hb ? x0 : a0;
  w[1] = hb ? x1 : a1;
  w[2] = hb ? a2 : x2;
  w[3] = hb ? a3 : x3;
  return __builtin_bit_cast(bf8, w);
}

__device__ __forceinline__ void attn_tile(
    const bf8 k0[4], const bf8 k1[4], const bf8 v0[4], const bf8 v1[4],
    const bf8 q[4], f16v& acc0, f16v& acc1, float& m, float& lsum, bool hb){
  f16v SA = {}, SB = {};
  #pragma unroll
  for (int sl=0; sl<4; sl++){
    SA = mfma32(k0[sl], q[sl], SA);   // s-subtile 0..31
    SB = mfma32(k1[sl], q[sl], SB);   // s-subtile 32..63
  }
  float t8[8];
  #pragma unroll
  for (int i=0;i<8;i++)
    t8[i] = fmaxf(fmaxf(SA[2*i],SA[2*i+1]), fmaxf(SB[2*i],SB[2*i+1]));
  float mx = fmaxf(fmaxf(fmaxf(t8[0],t8[1]), fmaxf(t8[2],t8[3])),
                   fmaxf(fmaxf(t8[4],t8[5]), fmaxf(t8[6],t8[7])));
  mx = fmaxf(mx, __shfl_xor(mx, 32));
  // defer-max (T13): only rescale when the running max grew by > 8 (P bounded by 2^8)
  if (!__all(mx <= m + 8.f)){
    const float mn = fmaxf(m, mx);
    const float crr = exp2f(m - mn);
    m = mn; lsum *= crr;
    #pragma unroll
    for (int i=0;i<16;i++){ acc0[i] *= crr; acc1[i] *= crr; }
  }
  #pragma unroll
  for (int i=0;i<16;i++){ SA[i] = exp2f(SA[i]-m); SB[i] = exp2f(SB[i]-m); }
  float s8[8];
  #pragma unroll
  for (int i=0;i<8;i++)
    s8[i] = (SA[2*i]+SA[2*i+1]) + (SB[2*i]+SB[2*i+1]);
  float ts = ((s8[0]+s8[1])+(s8[2]+s8[3])) + ((s8[4]+s8[5])+(s8[6]+s8[7]));
  ts += __shfl_xor(ts, 32);
  lsum += ts;
  // P -> bf16 pairs; cross-half exchange via verified shfl_xor pfrag
  u32 PA[8], PB[8];
  #pragma unroll
  for (int p=0;p<8;p++){
    PA[p] = cvtpk(SA[2*p], SA[2*p+1]);
    PB[p] = cvtpk(SB[2*p], SB[2*p+1]);
  }
  const bf8 pf0 = pfrag(PA[0],PA[1],PA[2],PA[3], hb);   // s 0..15
  const bf8 pf1 = pfrag(PA[4],PA[5],PA[6],PA[7], hb);   // s 16..31
  const bf8 pf2 = pfrag(PB[0],PB[1],PB[2],PB[3], hb);   // s 32..47
  const bf8 pf3 = pfrag(PB[4],PB[5],PB[6],PB[7], hb);   // s 48..63
  acc0 = mfma32(v0[0], pf0, acc0);  acc1 = mfma32(v1[0], pf0, acc1);
  acc0 = mfma32(v0[1], pf1, acc0);  acc1 = mfma32(v1[1], pf1, acc1);
  acc0 = mfma32(v0[2], pf2, acc0);  acc1 = mfma32(v1[2], pf2, acc1);
  acc0 = mfma32(v0[3], pf3, acc0);  acc1 = mfma32(v1[3], pf3, acc1);
}

// grid 1024; block = 4 waves: wave w -> qtile (w&1), s-half (w>>1).
// Wave pair (w, w+2) covers the same 32 q-rows over disjoint s halves; merged via LDS.
__global__ __launch_bounds__(256,4) void attn5(
    const u16* __restrict__ qF, const u16* __restrict__ kF,
    const u16* __restrict__ vF, u16* __restrict__ aT){
  __shared__ float lMrg[2*64*35];               // [pair slot][lane][m,l,acc0[16],acc1[16]] pad->35
  const int bid = blockIdx.x;                   // 1024 blocks
  const int bh = (bid&7)*2 + ((bid>>3)&1);      // XCD-pinned head pair
  const int qc = bid>>4;                        // 0..63 (64-row chunk)
  const int w  = threadIdx.x>>6;
  const int qt = qc*64 + (w&1)*32;
  const int shalf = w>>1;
  const int lane = threadIdx.x & 63, r = lane & 31, h = lane>>5;
  const bool hb = h != 0;

  bf8 q[4];
  const u16* qb = qF + (size_t)bh*FRAG_BH + (size_t)(qt>>5)*2048 + h*256 + r*8;
  #pragma unroll
  for (int sl=0; sl<4; sl++) q[sl] = *(const bf8*)(qb + sl*512);

  const u16* kl = kF + (size_t)bh*FRAG_BH + h*256 + r*8;
  const u16* vl = vF + (size_t)bh*FRAG_BH + h*512 + r*8;

  f16v acc0 = {}, acc1 = {};
  float m = -3e38f, lsum = 0.f;

  const int t0 = shalf*32;                      // 32 tiles of 64 per half
  bf8 kA0[4],kA1[4], kB0[4],kB1[4], v0[4],v1[4];
  loadKF(kl, t0, kA0, kA1);
  for (int t=t0; t<t0+32; t+=2){
    loadVF(vl, t, v0, v1);
    loadKF(kl, t+1, kB0, kB1);                    // prefetch K tile B
    attn_tile(kA0,kA1, v0,v1, q, acc0,acc1, m,lsum, hb);
    loadVF(vl, t+1, v0, v1);
    const int nx = (t+2 < t0+32) ? t+2 : t0;      // clamped prefetch A'
    loadKF(kl, nx, kA0, kA1);
    attn_tile(kB0,kB1, v0,v1, q, acc0,acc1, m,lsum, hb);
  }

  // merge wave pair (w, w+2): waves 2,3 publish state; waves 0,1 combine + store.
  if (w >= 2){
    float* dst = lMrg + ((w-2)*64 + lane)*35;
    dst[0] = m; dst[1] = lsum;
    #pragma unroll
    for (int i=0;i<16;i++){ dst[2+i] = acc0[i]; dst[18+i] = acc1[i]; }
  }
  __syncthreads();
  if (w < 2){
    const float* src = lMrg + (w*64 + lane)*35;
    const float m2 = src[0], l2 = src[1];
    const float mN = fmaxf(m, m2);
    const float cA = exp2f(m - mN), cB = exp2f(m2 - mN);
    lsum = lsum*cA + l2*cB;
    #pragma unroll
    for (int i=0;i<16;i++){
      acc0[i] = acc0[i]*cA + src[2+i]*cB;
      acc1[i] = acc1[i]*cA + src[18+i]*cB;
    }
    const float inv = 1.f/lsum;
    u16* op = aT + ((size_t)bh*LTOK + qt + r)*64;
    #pragma unroll
    for (int qd=0; qd<4; qd++){
      u32x2 w0, w1;
      w0[0] = cvtpk(acc0[4*qd]*inv,   acc0[4*qd+1]*inv);
      w0[1] = cvtpk(acc0[4*qd+2]*inv, acc0[4*qd+3]*inv);
      *(u32x2*)(op + 8*qd + (h?4:0)) = w0;          // c = 8qd+4h+{0..3}
      w1[0] = cvtpk(acc1[4*qd]*inv,   acc1[4*qd+1]*inv);
      w1[1] = cvtpk(acc1[4*qd+2]*inv, acc1[4*qd+3]*inv);
      *(u32x2*)(op + 32 + 8*qd + (h?4:0)) = w1;     // c = 32+8qd+4h+{0..3}
    }
  }
}

// ---------------- proj GEMM + bias + residual ----------------
__global__ __launch_bounds__(256) void proj_gemm(
    const u16* __restrict__ aT, const u16* __restrict__ wp,
    const float* __restrict__ bp, const float* __restrict__ x,
    float* __restrict__ out){
  __shared__ __align__(16) char lA[16384];   // [128 o][64 c]
  __shared__ __align__(16) char lB[16384];   // [128 l][64 c]
  const int l0 = blockIdx.x*128, o0 = blockIdx.y*128, b = blockIdx.z;
  const int tid = threadIdx.x, w = tid>>6, lane = tid&63;
  const int wm = w>>1, wn = w&1, fr = lane&15, g = lane>>4;
  f4 acc[4][4] = {};
  for (int kt=0; kt<8; kt++){
    const char* Ab = (const char*)(wp + (size_t)o0*CDIM + kt*64);
    const char* Bb = (const char*)(aT + ((size_t)(b*NHEADS + kt)*LTOK + l0)*64);
    #pragma unroll
    for (int j=0;j<4;j++){
      const int off = w*4096 + j*1024 + lane*16;
      const int row = off>>7, inrow = off&127;
      gload16(Ab + (size_t)row*1024 + SWZ(row,inrow), lA + w*4096 + j*1024);
      gload16(Bb + (size_t)row*128  + SWZ(row,inrow), lB + w*4096 + j*1024);
    }
    __syncthreads();
    bf8 af[4][2], bfr[4][2];
    #pragma unroll
    for (int mt=0;mt<4;mt++){
      #pragma unroll
      for (int kk=0;kk<2;kk++){
        const int row = wm*64 + mt*16 + fr;
        af[mt][kk] = *(const bf8*)(lA + row*128 + SWZ(row, kk*64 + g*16));
      }
    }
    #pragma unroll
    for (int nt=0;nt<4;nt++){
      #pragma unroll
      for (int kk=0;kk<2;kk++){
        const int row = wn*64 + nt*16 + fr;
        bfr[nt][kk] = *(const bf8*)(lB + row*128 + SWZ(row, kk*64 + g*16));
      }
    }
    #pragma unroll
    for (int mt=0;mt<4;mt++){
      #pragma unroll
      for (int nt=0;nt<4;nt++){
        acc[mt][nt] = mfma16(af[mt][0], bfr[nt][0], acc[mt][nt]);
        acc[mt][nt] = mfma16(af[mt][1], bfr[nt][1], acc[mt][nt]);
      }
    }
    __syncthreads();
  }
  // lane holds D[o = o0+wm*64+mt*16+g*4+r][l = l0+wn*64+nt*16+fr]
  #pragma unroll
  for (int mt=0;mt<4;mt++){
    #pragma unroll
    for (int r=0;r<4;r++){
      const int o = o0 + wm*64 + mt*16 + g*4 + r;
      const float bias = bp[o];
      #pragma unroll
      for (int nt=0;nt<4;nt++){
        const int l = l0 + wn*64 + nt*16 + fr;
        const size_t idx = ((size_t)b*CDIM + o)*LTOK + l;
        out[idx] = x[idx] + bias + acc[mt][nt][r];
      }
    }
  }
}

extern "C" void kernel_launch(void* const* d_in, const int* in_sizes, int n_in,
                              void* d_out, int out_size, void* d_ws, size_t ws_size,
                              hipStream_t stream){
  const float* x     = (const float*)d_in[0];
  const float* gamma = (const float*)d_in[1];
  const float* beta  = (const float*)d_in[2];
  const float* wqkv  = (const float*)d_in[3];
  const float* bqkv  = (const float*)d_in[4];
  const float* wproj = (const float*)d_in[5];
  const float* bproj = (const float*)d_in[6];
  float* out = (float*)d_out;

  char* ws = (char*)d_ws;
  u16* xnT = (u16*)ws;  ws += (size_t)2*LTOK*CDIM*2;     // 8 MB  [b][l][c]; aT aliases this later
  u16* qF  = (u16*)ws;  ws += (size_t)16*FRAG_BH*2;      // 8 MB  fragment-order Q (pre-scaled)
  u16* kF  = (u16*)ws;  ws += (size_t)16*FRAG_BH*2;      // 8 MB  fragment-order K (pre-scaled)
  u16* vF  = (u16*)ws;  ws += (size_t)16*FRAG_BH*2;      // 8 MB  fragment-order V
  u16* wqb = (u16*)ws;  ws += (size_t)1536*CDIM*2;       // 1.5 MB
  u16* wpb = (u16*)ws;  ws += (size_t)CDIM*CDIM*2;       // 0.5 MB
  float* stats = (float*)ws; ws += 64*2*sizeof(float);
  u16* aT = xnT;   // alias: xnT dead after qkv_gemm, aT born in attn
  if ((size_t)(ws - (char*)d_ws) > ws_size) return;      // ws too small -> loud validation failure

  gn_stats <<<dim3(64),     dim3(256), 0, stream>>>(x, stats);
  gn_norm_t<<<dim3(64,8,2), dim3(256), 0, stream>>>(x, gamma, beta, stats, xnT);
  cvt_bf16 <<<dim3(768),    dim3(256), 0, stream>>>(wqkv,  wqb, 1536*CDIM/4);
  cvt_bf16 <<<dim3(256),    dim3(256), 0, stream>>>(wproj, wpb, CDIM*CDIM/4);
  qkv_gemm <<<dim3(32,12,2),dim3(256), 0, stream>>>(xnT, wqb, bqkv, qF, kF, vF);
  attn5    <<<dim3(1024),   dim3(256), 0, stream>>>(qF, kF, vF, aT);
  proj_gemm<<<dim3(32,4,2), dim3(256), 0, stream>>>(aT, wpb, bproj, x, out);
}

// Round 12
// 308.638 us; speedup vs baseline: 2.0118x; 2.0118x over previous
//
#include <hip/hip_runtime.h>
#include <stdint.h>

// AttentionBlock: GroupNorm(32) -> 1x1 QKV -> 8-head legacy attention -> 1x1 proj -> residual
// B=2, C=512, H=W=64 (L=4096), heads=8, ch=64.
// attn v6: swapped 32x32x16 MFMA flash attention, fragment-order Q/K/V, split-S wave pairs.
// Round-11 post-mortem: launch_bounds(256,4) capped regs at ~128 -> spills -> 2.1GB scratch
// traffic. Fix: (256,3) => 12 waves/CU, ~170-reg cap, no spill, 1.5x attn4's occupancy.

#define LTOK 4096
#define CDIM 512
#define NHEADS 8
#define EPS_GN 1e-6f
#define QKSCALE 0.3535533905932738f            // 1/sqrt(sqrt(64))
#define QSCL (0.3535533905932738f * 1.44269504088896f)  // LOG2E folded into q
#define FRAG_BH 262144                          // elems per bh in qF/kF/vF (=4096*64)

typedef float  f4   __attribute__((ext_vector_type(4)));
typedef float  f16v __attribute__((ext_vector_type(16)));
typedef short  bf8  __attribute__((ext_vector_type(8)));   // 8 bf16 as shorts
typedef unsigned short u16;
typedef unsigned short u16x8 __attribute__((ext_vector_type(8)));
typedef unsigned short u16x4 __attribute__((ext_vector_type(4)));
typedef uint32_t u32;
typedef uint32_t u32x2 __attribute__((ext_vector_type(2)));
typedef uint32_t u32x4 __attribute__((ext_vector_type(4)));

// T2 XOR swizzle for 128B-row LDS tiles (GEMM kernels): involution on 16B chunks.
#define SWZ(row, inrow) ((inrow) ^ (((row)&7)<<4))

__device__ __forceinline__ u16 f2bf(float f){
  uint32_t u = __builtin_bit_cast(uint32_t, f);
  u += 0x7FFFu + ((u>>16)&1u);           // RNE
  return (u16)(u>>16);
}
// width=16 global->LDS DMA (GEMM staging). LDS dest wave-uniform; global src per-lane.
__device__ __forceinline__ void gload16(const void* g, void* l){
  __builtin_amdgcn_global_load_lds(
      (const __attribute__((address_space(1))) uint32_t*)g,
      (__attribute__((address_space(3))) uint32_t*)l, 16, 0, 0);
}
__device__ __forceinline__ f4 mfma16(bf8 a, bf8 b, f4 c){
  return __builtin_amdgcn_mfma_f32_16x16x32_bf16(a, b, c, 0, 0, 0);
}
__device__ __forceinline__ f16v mfma32(bf8 a, bf8 b, f16v c){
  return __builtin_amdgcn_mfma_f32_32x32x16_bf16(a, b, c, 0, 0, 0);
}
__device__ __forceinline__ u32 cvtpk(float a, float b){
  u32 d;
  asm("v_cvt_pk_bf16_f32 %0, %1, %2" : "=v"(d) : "v"(a), "v"(b));
  return d;
}

// ---------------- GroupNorm ----------------
__global__ __launch_bounds__(256) void gn_stats(const float* __restrict__ x,
                                                float* __restrict__ stats){
  const int bg = blockIdx.x;                   // b*32+g
  const float* p = x + (size_t)bg * 16 * LTOK;
  float s1 = 0.f, s2 = 0.f;
  for (int i = threadIdx.x; i < 16*LTOK/4; i += 256){
    f4 v = ((const f4*)p)[i];
    s1 += v[0]+v[1]+v[2]+v[3];
    s2 += v[0]*v[0]+v[1]*v[1]+v[2]*v[2]+v[3]*v[3];
  }
  #pragma unroll
  for (int off=32; off; off>>=1){ s1 += __shfl_down(s1, off); s2 += __shfl_down(s2, off); }
  __shared__ float a1[4], a2[4];
  const int w = threadIdx.x>>6;
  if ((threadIdx.x&63)==0){ a1[w]=s1; a2[w]=s2; }
  __syncthreads();
  if (threadIdx.x==0){
    float t1 = a1[0]+a1[1]+a1[2]+a1[3];
    float t2 = a2[0]+a2[1]+a2[2]+a2[3];
    const float inv = 1.f/(16.f*LTOK);
    float mu  = t1*inv;
    float var = t2*inv - mu*mu;
    stats[bg*2]   = mu;
    stats[bg*2+1] = rsqrtf(var + EPS_GN);
  }
}

// normalize + transpose to xnT[b][l][c] bf16
__global__ __launch_bounds__(256) void gn_norm_t(
    const float* __restrict__ x, const float* __restrict__ gamma,
    const float* __restrict__ beta, const float* __restrict__ stats,
    u16* __restrict__ xnT){
  __shared__ float t[64][65];
  const int lb = blockIdx.x*64, cb = blockIdx.y*64, b = blockIdx.z;
  const int tid = threadIdx.x;
  {
    const int cl = tid>>4;         // 0..15
    const int ll = (tid&15)*4;     // 0..60
    #pragma unroll
    for (int rep=0; rep<4; rep++){
      const int cloc = rep*16 + cl;
      const int c = cb + cloc;
      const int grp = c>>4;
      const float mu = stats[(b*32+grp)*2];
      const float rs = stats[(b*32+grp)*2+1];
      const float ga = gamma[c], be = beta[c];
      f4 v = *(const f4*)(x + ((size_t)b*CDIM + c)*LTOK + lb + ll);
      t[cloc][ll+0] = (v[0]-mu)*rs*ga + be;
      t[cloc][ll+1] = (v[1]-mu)*rs*ga + be;
      t[cloc][ll+2] = (v[2]-mu)*rs*ga + be;
      t[cloc][ll+3] = (v[3]-mu)*rs*ga + be;
    }
  }
  __syncthreads();
  {
    const int l2 = tid>>2;            // 0..63
    const int c2 = (tid&3)*16;        // 0,16,32,48
    u16x8 o0, o1;
    #pragma unroll
    for (int j=0;j<8;j++){
      o0[j] = f2bf(t[c2+j][l2]);
      o1[j] = f2bf(t[c2+8+j][l2]);
    }
    u16* dst = xnT + ((size_t)b*LTOK + lb + l2)*CDIM + cb + c2;
    *(u16x8*)dst       = o0;
    *((u16x8*)dst + 1) = o1;
  }
}

// ---------------- f32 -> bf16 weight convert ----------------
__global__ __launch_bounds__(256) void cvt_bf16(const float* __restrict__ in,
                                                u16* __restrict__ out, int n4){
  int i = blockIdx.x*256 + threadIdx.x;
  if (i >= n4) return;
  f4 v = ((const f4*)in)[i];
  u16x4 o;
  o[0]=f2bf(v[0]); o[1]=f2bf(v[1]); o[2]=f2bf(v[2]); o[3]=f2bf(v[3]);
  ((u16x4*)out)[i] = o;
}

// ---------------- QKV GEMM ----------------
// D[l][o] = sum_c xnT[l][c] * W[o][c]
// epilogue writes FRAGMENT-ORDER q/k/v:
//   qF/kF[bh]: elem = ((tile32*4 + sl)*2 + h)*256 + row*8 + j   (t=tile32*32+row, c=16sl+8h+j)
//   vF[bh]:    elem = ((tile64*4 + ks)*2 + h)*512 + c*8 + j     (s=tile64*64+16ks+8h+j)
__global__ __launch_bounds__(256) void qkv_gemm(
    const u16* __restrict__ xnT, const u16* __restrict__ wqkv,
    const float* __restrict__ bqkv,
    u16* __restrict__ qF, u16* __restrict__ kF, u16* __restrict__ vF){
  __shared__ __align__(16) char lA[16384];   // [128 l][64 k] bf16, swizzled
  __shared__ __align__(16) char lB[16384];   // [128 o][64 k] bf16, swizzled
  const int l0 = blockIdx.x*128, o0 = blockIdx.y*128, b = blockIdx.z;
  const int tid = threadIdx.x, w = tid>>6, lane = tid&63;
  const int wm = w>>1, wn = w&1, fr = lane&15, g = lane>>4;
  f4 acc[4][4] = {};
  const char* Ab = (const char*)(xnT + ((size_t)b*LTOK + l0)*CDIM);
  const char* Bb = (const char*)(wqkv + (size_t)o0*CDIM);
  for (int kt=0; kt<8; kt++){
    #pragma unroll
    for (int j=0;j<4;j++){
      const int off = w*4096 + j*1024 + lane*16;
      const int row = off>>7, inrow = off&127;
      gload16(Ab + (size_t)row*1024 + kt*128 + SWZ(row,inrow), lA + w*4096 + j*1024);
      gload16(Bb + (size_t)row*1024 + kt*128 + SWZ(row,inrow), lB + w*4096 + j*1024);
    }
    __syncthreads();
    bf8 af[4][2], bfr[4][2];
    #pragma unroll
    for (int mt=0;mt<4;mt++){
      #pragma unroll
      for (int kk=0;kk<2;kk++){
        const int row = wm*64 + mt*16 + fr;
        af[mt][kk] = *(const bf8*)(lA + row*128 + SWZ(row, kk*64 + g*16));
      }
    }
    #pragma unroll
    for (int nt=0;nt<4;nt++){
      #pragma unroll
      for (int kk=0;kk<2;kk++){
        const int row = wn*64 + nt*16 + fr;
        bfr[nt][kk] = *(const bf8*)(lB + row*128 + SWZ(row, kk*64 + g*16));
      }
    }
    #pragma unroll
    for (int mt=0;mt<4;mt++){
      #pragma unroll
      for (int nt=0;nt<4;nt++){
        acc[mt][nt] = mfma16(af[mt][0], bfr[nt][0], acc[mt][nt]);
        acc[mt][nt] = mfma16(af[mt][1], bfr[nt][1], acc[mt][nt]);
      }
    }
    __syncthreads();
  }
  // lane holds D[l = l0+wm*64+mt*16+g*4+r_][o = o0+wn*64+nt*16+fr]
  #pragma unroll
  for (int nt=0;nt<4;nt++){
    const int o = o0 + wn*64 + nt*16 + fr;
    const float bias = bqkv[o];
    const int head = o / 192;
    int rr = o - head*192;                 // legacy interleave: [q|k|v] x 64 per head
    const int bh = b*NHEADS + head;
    if (rr < 128){
      u16* base; float sc;
      if (rr < 64){ base = qF; sc = QSCL; }
      else        { base = kF; sc = QKSCALE; rr -= 64; }
      const int sl = rr>>4, hq = (rr>>3)&1, j = rr&7;
      const int Tb = (l0 + wm*64)>>5;                  // tile32 base
      u16* p = base + (size_t)bh*FRAG_BH + (size_t)(sl*2 + hq)*256 + j;
      #pragma unroll
      for (int mt=0;mt<4;mt++){
        const size_t toff = (size_t)(Tb + (mt>>1))*2048 + (size_t)((mt&1)*16 + g*4)*8;
        #pragma unroll
        for (int r_=0;r_<4;r_++)
          p[toff + r_*8] = f2bf((acc[mt][nt][r_] + bias) * sc);
      }
    } else {
      rr -= 128;                                       // rr = c
      const int s64 = (l0>>6) + wm;
      u16* p = vF + (size_t)bh*FRAG_BH + (size_t)s64*4096 + (size_t)(g>>1)*512
                  + (size_t)rr*8 + (g&1)*4;
      #pragma unroll
      for (int mt=0;mt<4;mt++){                        // ks = mt
        u16x4 pk;
        #pragma unroll
        for (int r_=0;r_<4;r_++) pk[r_] = f2bf(acc[mt][nt][r_] + bias);
        *(u16x4*)(p + mt*1024) = pk;
      }
    }
  }
}

// ---------------- flash attention v6 (split-S wave pairs, 3 blocks/CU) ----------------
__device__ __forceinline__ void loadKF(const u16* kl, int t64, bf8 k0[4], bf8 k1[4]){
  const u16* p = kl + (size_t)t64*4096;
  #pragma unroll
  for (int sl=0; sl<4; sl++){
    k0[sl] = *(const bf8*)(p + sl*512);           // s rows t64*64 + r
    k1[sl] = *(const bf8*)(p + 2048 + sl*512);    // s rows +32
  }
}
__device__ __forceinline__ void loadVF(const u16* vl, int t64, bf8 v0[4], bf8 v1[4]){
  const u16* p = vl + (size_t)t64*4096;
  #pragma unroll
  for (int ks=0; ks<4; ks++){
    v0[ks] = *(const bf8*)(p + ks*1024);          // c rows 0..31
    v1[ks] = *(const bf8*)(p + ks*1024 + 256);    // c rows 32..63
  }
}
// Build one PV B-fragment (k-slice of 16 s) from 4 packed u32 (P pairs).
// HW-VERIFIED form (rounds 6/10/11 passed validation with this exact structure).
__device__ __forceinline__ bf8 pfrag(u32 a0, u32 a1, u32 a2, u32 a3, bool hb){
  u32 x0 = (u32)__shfl_xor((int)a2, 32);
  u32 x1 = (u32)__shfl_xor((int)a3, 32);
  u32 x2 = (u32)__shfl_xor((int)a0, 32);
  u32 x3 = (u32)__shfl_xor((int)a1, 32);
  u32x4 w;
  w[0] = hb ? x0 : a0;
  w[1] = hb ? x1 : a1;
  w[2] = hb ? a2 : x2;
  w[3] = hb ? a3 : x3;
  return __builtin_bit_cast(bf8, w);
}

__device__ __forceinline__ void attn_tile(
    const bf8 k0[4], const bf8 k1[4], const bf8 v0[4], const bf8 v1[4],
    const bf8 q[4], f16v& acc0, f16v& acc1, float& m, float& lsum, bool hb){
  f16v SA = {}, SB = {};
  #pragma unroll
  for (int sl=0; sl<4; sl++){
    SA = mfma32(k0[sl], q[sl], SA);   // s-subtile 0..31
    SB = mfma32(k1[sl], q[sl], SB);   // s-subtile 32..63
  }
  float t8[8];
  #pragma unroll
  for (int i=0;i<8;i++)
    t8[i] = fmaxf(fmaxf(SA[2*i],SA[2*i+1]), fmaxf(SB[2*i],SB[2*i+1]));
  float mx = fmaxf(fmaxf(fmaxf(t8[0],t8[1]), fmaxf(t8[2],t8[3])),
                   fmaxf(fmaxf(t8[4],t8[5]), fmaxf(t8[6],t8[7])));
  mx = fmaxf(mx, __shfl_xor(mx, 32));
  // defer-max (T13): only rescale when the running max grew by > 8 (P bounded by 2^8)
  if (!__all(mx <= m + 8.f)){
    const float mn = fmaxf(m, mx);
    const float crr = exp2f(m - mn);
    m = mn; lsum *= crr;
    #pragma unroll
    for (int i=0;i<16;i++){ acc0[i] *= crr; acc1[i] *= crr; }
  }
  #pragma unroll
  for (int i=0;i<16;i++){ SA[i] = exp2f(SA[i]-m); SB[i] = exp2f(SB[i]-m); }
  float s8[8];
  #pragma unroll
  for (int i=0;i<8;i++)
    s8[i] = (SA[2*i]+SA[2*i+1]) + (SB[2*i]+SB[2*i+1]);
  float ts = ((s8[0]+s8[1])+(s8[2]+s8[3])) + ((s8[4]+s8[5])+(s8[6]+s8[7]));
  ts += __shfl_xor(ts, 32);
  lsum += ts;
  // P -> bf16 pairs; cross-half exchange via verified shfl_xor pfrag
  u32 PA[8], PB[8];
  #pragma unroll
  for (int p=0;p<8;p++){
    PA[p] = cvtpk(SA[2*p], SA[2*p+1]);
    PB[p] = cvtpk(SB[2*p], SB[2*p+1]);
  }
  const bf8 pf0 = pfrag(PA[0],PA[1],PA[2],PA[3], hb);   // s 0..15
  const bf8 pf1 = pfrag(PA[4],PA[5],PA[6],PA[7], hb);   // s 16..31
  const bf8 pf2 = pfrag(PB[0],PB[1],PB[2],PB[3], hb);   // s 32..47
  const bf8 pf3 = pfrag(PB[4],PB[5],PB[6],PB[7], hb);   // s 48..63
  acc0 = mfma32(v0[0], pf0, acc0);  acc1 = mfma32(v1[0], pf0, acc1);
  acc0 = mfma32(v0[1], pf1, acc0);  acc1 = mfma32(v1[1], pf1, acc1);
  acc0 = mfma32(v0[2], pf2, acc0);  acc1 = mfma32(v1[2], pf2, acc1);
  acc0 = mfma32(v0[3], pf3, acc0);  acc1 = mfma32(v1[3], pf3, acc1);
}

// grid 1024; block = 4 waves: wave w -> qtile (w&1), s-half (w>>1).
// Wave pair (w, w+2) covers the same 32 q-rows over disjoint s halves; merged via LDS.
// launch_bounds(256,3): 12 waves/CU, ~170-reg cap -> no spills (round-11 lesson).
__global__ __launch_bounds__(256,3) void attn6(
    const u16* __restrict__ qF, const u16* __restrict__ kF,
    const u16* __restrict__ vF, u16* __restrict__ aT){
  __shared__ float lMrg[2*64*35];               // [pair slot][lane][m,l,acc0[16],acc1[16]] pad->35
  const int bid = blockIdx.x;                   // 1024 blocks
  const int bh = (bid&7)*2 + ((bid>>3)&1);      // XCD-pinned head pair
  const int qc = bid>>4;                        // 0..63 (64-row chunk)
  const int w  = threadIdx.x>>6;
  const int qt = qc*64 + (w&1)*32;
  const int shalf = w>>1;
  const int lane = threadIdx.x & 63, r = lane & 31, h = lane>>5;
  const bool hb = h != 0;

  bf8 q[4];
  const u16* qb = qF + (size_t)bh*FRAG_BH + (size_t)(qt>>5)*2048 + h*256 + r*8;
  #pragma unroll
  for (int sl=0; sl<4; sl++) q[sl] = *(const bf8*)(qb + sl*512);

  const u16* kl = kF + (size_t)bh*FRAG_BH + h*256 + r*8;
  const u16* vl = vF + (size_t)bh*FRAG_BH + h*512 + r*8;

  f16v acc0 = {}, acc1 = {};
  float m = -3e38f, lsum = 0.f;

  const int t0 = shalf*32;                      // 32 tiles of 64 per half
  bf8 kA0[4],kA1[4], kB0[4],kB1[4], v0[4],v1[4];
  loadKF(kl, t0, kA0, kA1);
  for (int t=t0; t<t0+32; t+=2){
    loadVF(vl, t, v0, v1);
    loadKF(kl, t+1, kB0, kB1);                    // prefetch K tile B
    attn_tile(kA0,kA1, v0,v1, q, acc0,acc1, m,lsum, hb);
    loadVF(vl, t+1, v0, v1);
    const int nx = (t+2 < t0+32) ? t+2 : t0;      // clamped prefetch A'
    loadKF(kl, nx, kA0, kA1);
    attn_tile(kB0,kB1, v0,v1, q, acc0,acc1, m,lsum, hb);
  }

  // merge wave pair (w, w+2): waves 2,3 publish state; waves 0,1 combine + store.
  if (w >= 2){
    float* dst = lMrg + ((w-2)*64 + lane)*35;
    dst[0] = m; dst[1] = lsum;
    #pragma unroll
    for (int i=0;i<16;i++){ dst[2+i] = acc0[i]; dst[18+i] = acc1[i]; }
  }
  __syncthreads();
  if (w < 2){
    const float* src = lMrg + (w*64 + lane)*35;
    const float m2 = src[0], l2 = src[1];
    const float mN = fmaxf(m, m2);
    const float cA = exp2f(m - mN), cB = exp2f(m2 - mN);
    lsum = lsum*cA + l2*cB;
    #pragma unroll
    for (int i=0;i<16;i++){
      acc0[i] = acc0[i]*cA + src[2+i]*cB;
      acc1[i] = acc1[i]*cA + src[18+i]*cB;
    }
    const float inv = 1.f/lsum;
    u16* op = aT + ((size_t)bh*LTOK + qt + r)*64;
    #pragma unroll
    for (int qd=0; qd<4; qd++){
      u32x2 w0, w1;
      w0[0] = cvtpk(acc0[4*qd]*inv,   acc0[4*qd+1]*inv);
      w0[1] = cvtpk(acc0[4*qd+2]*inv, acc0[4*qd+3]*inv);
      *(u32x2*)(op + 8*qd + (h?4:0)) = w0;          // c = 8qd+4h+{0..3}
      w1[0] = cvtpk(acc1[4*qd]*inv,   acc1[4*qd+1]*inv);
      w1[1] = cvtpk(acc1[4*qd+2]*inv, acc1[4*qd+3]*inv);
      *(u32x2*)(op + 32 + 8*qd + (h?4:0)) = w1;     // c = 32+8qd+4h+{0..3}
    }
  }
}

// ---------------- proj GEMM + bias + residual ----------------
__global__ __launch_bounds__(256) void proj_gemm(
    const u16* __restrict__ aT, const u16* __restrict__ wp,
    const float* __restrict__ bp, const float* __restrict__ x,
    float* __restrict__ out){
  __shared__ __align__(16) char lA[16384];   // [128 o][64 c]
  __shared__ __align__(16) char lB[16384];   // [128 l][64 c]
  const int l0 = blockIdx.x*128, o0 = blockIdx.y*128, b = blockIdx.z;
  const int tid = threadIdx.x, w = tid>>6, lane = tid&63;
  const int wm = w>>1, wn = w&1, fr = lane&15, g = lane>>4;
  f4 acc[4][4] = {};
  for (int kt=0; kt<8; kt++){
    const char* Ab = (const char*)(wp + (size_t)o0*CDIM + kt*64);
    const char* Bb = (const char*)(aT + ((size_t)(b*NHEADS + kt)*LTOK + l0)*64);
    #pragma unroll
    for (int j=0;j<4;j++){
      const int off = w*4096 + j*1024 + lane*16;
      const int row = off>>7, inrow = off&127;
      gload16(Ab + (size_t)row*1024 + SWZ(row,inrow), lA + w*4096 + j*1024);
      gload16(Bb + (size_t)row*128  + SWZ(row,inrow), lB + w*4096 + j*1024);
    }
    __syncthreads();
    bf8 af[4][2], bfr[4][2];
    #pragma unroll
    for (int mt=0;mt<4;mt++){
      #pragma unroll
      for (int kk=0;kk<2;kk++){
        const int row = wm*64 + mt*16 + fr;
        af[mt][kk] = *(const bf8*)(lA + row*128 + SWZ(row, kk*64 + g*16));
      }
    }
    #pragma unroll
    for (int nt=0;nt<4;nt++){
      #pragma unroll
      for (int kk=0;kk<2;kk++){
        const int row = wn*64 + nt*16 + fr;
        bfr[nt][kk] = *(const bf8*)(lB + row*128 + SWZ(row, kk*64 + g*16));
      }
    }
    #pragma unroll
    for (int mt=0;mt<4;mt++){
      #pragma unroll
      for (int nt=0;nt<4;nt++){
        acc[mt][nt] = mfma16(af[mt][0], bfr[nt][0], acc[mt][nt]);
        acc[mt][nt] = mfma16(af[mt][1], bfr[nt][1], acc[mt][nt]);
      }
    }
    __syncthreads();
  }
  // lane holds D[o = o0+wm*64+mt*16+g*4+r][l = l0+wn*64+nt*16+fr]
  #pragma unroll
  for (int mt=0;mt<4;mt++){
    #pragma unroll
    for (int r=0;r<4;r++){
      const int o = o0 + wm*64 + mt*16 + g*4 + r;
      const float bias = bp[o];
      #pragma unroll
      for (int nt=0;nt<4;nt++){
        const int l = l0 + wn*64 + nt*16 + fr;
        const size_t idx = ((size_t)b*CDIM + o)*LTOK + l;
        out[idx] = x[idx] + bias + acc[mt][nt][r];
      }
    }
  }
}

extern "C" void kernel_launch(void* const* d_in, const int* in_sizes, int n_in,
                              void* d_out, int out_size, void* d_ws, size_t ws_size,
                              hipStream_t stream){
  const float* x     = (const float*)d_in[0];
  const float* gamma = (const float*)d_in[1];
  const float* beta  = (const float*)d_in[2];
  const float* wqkv  = (const float*)d_in[3];
  const float* bqkv  = (const float*)d_in[4];
  const float* wproj = (const float*)d_in[5];
  const float* bproj = (const float*)d_in[6];
  float* out = (float*)d_out;

  char* ws = (char*)d_ws;
  u16* xnT = (u16*)ws;  ws += (size_t)2*LTOK*CDIM*2;     // 8 MB  [b][l][c]; aT aliases this later
  u16* qF  = (u16*)ws;  ws += (size_t)16*FRAG_BH*2;      // 8 MB  fragment-order Q (pre-scaled)
  u16* kF  = (u16*)ws;  ws += (size_t)16*FRAG_BH*2;      // 8 MB  fragment-order K (pre-scaled)
  u16* vF  = (u16*)ws;  ws += (size_t)16*FRAG_BH*2;      // 8 MB  fragment-order V
  u16* wqb = (u16*)ws;  ws += (size_t)1536*CDIM*2;       // 1.5 MB
  u16* wpb = (u16*)ws;  ws += (size_t)CDIM*CDIM*2;       // 0.5 MB
  float* stats = (float*)ws; ws += 64*2*sizeof(float);
  u16* aT = xnT;   // alias: xnT dead after qkv_gemm, aT born in attn
  if ((size_t)(ws - (char*)d_ws) > ws_size) return;      // ws too small -> loud validation failure

  gn_stats <<<dim3(64),     dim3(256), 0, stream>>>(x, stats);
  gn_norm_t<<<dim3(64,8,2), dim3(256), 0, stream>>>(x, gamma, beta, stats, xnT);
  cvt_bf16 <<<dim3(768),    dim3(256), 0, stream>>>(wqkv,  wqb, 1536*CDIM/4);
  cvt_bf16 <<<dim3(256),    dim3(256), 0, stream>>>(wproj, wpb, CDIM*CDIM/4);
  qkv_gemm <<<dim3(32,12,2),dim3(256), 0, stream>>>(xnT, wqb, bqkv, qF, kF, vF);
  attn6    <<<dim3(1024),   dim3(256), 0, stream>>>(qF, kF, vF, aT);
  proj_gemm<<<dim3(32,4,2), dim3(256), 0, stream>>>(aT, wpb, bproj, x, out);
}